// Round 3
// baseline (544.343 us; speedup 1.0000x reference)
//
#include <hip/hip_runtime.h>

// Problem constants
#define DD   256
#define SEQ  128
#define NB   32
#define VOC  32000
#define ROWS (NB * SEQ)   // 4096
#define KK   512          // 2*D (real|imag concat)

typedef __attribute__((ext_vector_type(8))) short short8;
typedef __attribute__((ext_vector_type(4))) float f32x4;

__device__ inline unsigned short f2bf(float f) {
  unsigned int u = __float_as_uint(f);
  u += 0x7FFF + ((u >> 16) & 1);   // RNE
  return (unsigned short)(u >> 16);
}

__device__ inline void gload16(const void* g, void* l) {
  __builtin_amdgcn_global_load_lds(
      (const __attribute__((address_space(1))) void*)g,
      (__attribute__((address_space(3))) void*)l, 16, 0, 0);
}

// K0: pack W rows = [wr | wi] -> bf16, bias = br + bi
__global__ __launch_bounds__(256) void k_prep(
    const float* __restrict__ wr, const float* __restrict__ wi,
    const float* __restrict__ br, const float* __restrict__ bi,
    unsigned short* __restrict__ Wb, float* __restrict__ bias) {
  int idx = blockIdx.x * 256 + threadIdx.x;   // one 4-elem chunk
  int v = idx >> 7, c = idx & 127;
  const float* src = (c < 64) ? (wr + (size_t)v * DD + c * 4)
                              : (wi + (size_t)v * DD + (c - 64) * 4);
  float4 f = *(const float4*)src;
  ushort4 o;
  o.x = f2bf(f.x); o.y = f2bf(f.y); o.z = f2bf(f.z); o.w = f2bf(f.w);
  *(ushort4*)(Wb + (size_t)v * KK + c * 4) = o;
  if (c == 0) bias[v] = br[v] + bi[v];
}

// K1: mag = tanh(emb[x]); state/q/k/v real+imag parts (rot by constant phase)
__global__ __launch_bounds__(256) void k_embed(
    const int* __restrict__ x, const float* __restrict__ emb,
    const float* __restrict__ qrot, const float* __restrict__ krot,
    const float* __restrict__ vrot,
    float* __restrict__ Sb, float* __restrict__ Qb,
    float* __restrict__ Kb, float* __restrict__ Vb) {
  int row = blockIdx.x;          // b*SEQ + s
  int s = row & (SEQ - 1);
  int d = threadIdx.x;
  int tok = x[row];
  float m = tanhf(emb[(size_t)tok * DD + d]);
  float freq = expf(-(float)d * (9.210340371976184f / 256.f)); // 10000^(-d/256)
  float p = (float)s * freq * 3.14159265358979f;
  float sn, cs;
  size_t base = (size_t)row * KK + d;
  sincosf(p, &sn, &cs);             Sb[base] = m * cs; Sb[base + DD] = m * sn;
  float a;
  a = p + qrot[d]; sincosf(a, &sn, &cs); Qb[base] = m * cs; Qb[base + DD] = m * sn;
  a = p + krot[d]; sincosf(a, &sn, &cs); Kb[base] = m * cs; Kb[base + DD] = m * sn;
  a = p + vrot[d]; sincosf(a, &sn, &cs); Vb[base] = m * cs; Vb[base + DD] = m * sn;
}

// K2: one block per (b,s): causal logits (dot*0.5), softmax, PV, residual add
__global__ __launch_bounds__(256) void k_attn(
    const float* __restrict__ Qb, const float* __restrict__ Kb,
    const float* __restrict__ Vb, const float* __restrict__ Sb,
    float* __restrict__ S2) {
  int row = blockIdx.x;
  int b = row >> 7, s = row & 127;
  int tid = threadIdx.x;
  __shared__ __align__(16) float q[KK];
  __shared__ float w[SEQ];
  __shared__ float smax, ssum;
  q[tid] = Qb[(size_t)row * KK + tid];
  q[tid + 256] = Qb[(size_t)row * KK + 256 + tid];
  __syncthreads();
  int t = tid >> 1, half = tid & 1;
  const float4* q4 = (const float4*)(q + half * 256);
  const float4* k4 = (const float4*)(Kb + ((size_t)(b * SEQ + t)) * KK + half * 256);
  float acc = 0.f;
  if (t <= s) {
#pragma unroll 4
    for (int i = 0; i < 64; ++i) {
      float4 qa = q4[i], ka = k4[i];
      acc += qa.x * ka.x + qa.y * ka.y + qa.z * ka.z + qa.w * ka.w;
    }
  }
  acc += __shfl_xor(acc, 1);
  if (half == 0) w[t] = (t <= s) ? acc * 0.5f : -INFINITY;
  __syncthreads();
  if (tid < 64) {
    float m2 = fmaxf(w[tid], w[tid + 64]);
    for (int o = 32; o; o >>= 1) m2 = fmaxf(m2, __shfl_xor(m2, o));
    if (tid == 0) smax = m2;
  }
  __syncthreads();
  if (tid < 128) w[tid] = expf(w[tid] - smax);
  __syncthreads();
  if (tid < 64) {
    float s2 = w[tid] + w[tid + 64];
    for (int o = 32; o; o >>= 1) s2 += __shfl_xor(s2, o);
    if (tid == 0) ssum = s2;
  }
  __syncthreads();
  float inv = 1.f / ssum;
  float o0 = 0.f, o1 = 0.f;
  const float* vb = Vb + (size_t)(b * SEQ) * KK;
  int nt = s + 1;
  for (int tt = 0; tt < nt; ++tt) {
    float wt = w[tt];
    o0 += wt * vb[(size_t)tt * KK + tid];
    o1 += wt * vb[(size_t)tt * KK + 256 + tid];
  }
  size_t base = (size_t)row * KK + tid;
  S2[base] = Sb[base] + o0 * inv;
  S2[base + 256] = Sb[base + 256] + o1 * inv;
}

// K3: complex FF (state @ (ffr + i*ffi)), complex_norm, cast to bf16 X
__global__ __launch_bounds__(256) void k_ffnorm(
    const float* __restrict__ S2, const float* __restrict__ ffr,
    const float* __restrict__ ffi, unsigned short* __restrict__ X) {
  int row0 = blockIdx.x * 4;
  int d = threadIdx.x;
  __shared__ __align__(16) float in[4][KK];
  __shared__ float mg[4][DD];
  __shared__ float stats[8];
#pragma unroll
  for (int i = 0; i < 8; ++i)
    ((float*)in)[i * 256 + d] = S2[(size_t)row0 * KK + i * 256 + d];
  __syncthreads();
  float nr[4] = {0, 0, 0, 0}, ni[4] = {0, 0, 0, 0};
  for (int e = 0; e < DD; ++e) {
    float fr = ffr[e * DD + d];
    float fi = ffi[e * DD + d];
#pragma unroll
    for (int r = 0; r < 4; ++r) {
      float a = in[r][e], c = in[r][DD + e];
      nr[r] += a * fr - c * fi;
      ni[r] += a * fi + c * fr;
    }
  }
#pragma unroll
  for (int r = 0; r < 4; ++r) mg[r][d] = sqrtf(nr[r] * nr[r] + ni[r] * ni[r]);
  __syncthreads();
  int wv = d >> 6, ln = d & 63;
  float s0 = mg[wv][ln] + mg[wv][ln + 64] + mg[wv][ln + 128] + mg[wv][ln + 192];
  for (int o = 32; o; o >>= 1) s0 += __shfl_xor(s0, o);
  float mean = s0 * (1.f / 256.f);
  float var = 0.f;
#pragma unroll
  for (int k = 0; k < 4; ++k) { float t2 = mg[wv][ln + k * 64] - mean; var += t2 * t2; }
  for (int o = 32; o; o >>= 1) var += __shfl_xor(var, o);
  if (ln == 0) { stats[wv * 2] = mean; stats[wv * 2 + 1] = sqrtf(var * (1.f / 255.f)); }
  __syncthreads();
#pragma unroll
  for (int r = 0; r < 4; ++r) {
    float mean2 = stats[r * 2], stdv = stats[r * 2 + 1];
    float mag = mg[r][d];
    float norm = (mag - mean2) / (stdv + 1e-5f);
    float sc = tanhf(norm) / (mag + 1e-5f);
    size_t base = (size_t)(row0 + r) * KK + d;
    X[base] = f2bf(nr[r] * sc);
    X[base + DD] = f2bf(ni[r] * sc);
  }
}

// K4: logits[4096][32000] = X[4096][512] * Wb[32000][512]^T + bias
// 256x256 tile, BK=32, 8 waves (2Mx4N), LDS double-buffer, 1 barrier/K-tile,
// global_load_lds with source-side XOR swizzle (rule #21), XCD-aware block map.
__global__ __launch_bounds__(512, 2) void k_gemm(
    const unsigned short* __restrict__ X, const unsigned short* __restrict__ Wb,
    const float* __restrict__ bias, float* __restrict__ out) {
  __shared__ __align__(16) unsigned short Ab[2][256 * 32];  // 32 KB
  __shared__ __align__(16) unsigned short Bb[2][256 * 32];  // 32 KB
  int tid = threadIdx.x;
  int lane = tid & 63, wave = tid >> 6;
  int wr = wave >> 2, wc = wave & 3;          // 2 x 4 wave grid
  // XCD-aware bijective swizzle: 2000 blocks = 8 XCDs x 250
  int orig = blockIdx.x;
  int wg = (orig & 7) * 250 + (orig >> 3);
  int mt = wg & 15, nt = wg >> 4;             // nt-major within XCD chunk
  size_t rowA0 = (size_t)mt * 256;
  size_t rowB0 = (size_t)nt * 256;
  // staging geometry: stripe = 16 rows x 32 elems (=1KB); 16 stripes per matrix
  // lane l -> row-in-stripe l>>2, chunk l&3; source chunk XOR'd (rule #21)
  int srow = lane >> 2;
  int schunk = ((lane & 3) ^ ((lane >> 2) & 3)) * 8;   // elems
  // fragment-read chunk (same XOR on read side): row&3 == lane&3 here
  int rchunk = (((lane >> 4) ^ (lane & 3))) * 8;        // elems
  int lane15 = lane & 15;

  f32x4 acc[8][4] = {};

  // prologue: stage K-tile 0 into buf 0
  {
#pragma unroll
    for (int i = 0; i < 2; ++i) {
      int c = wave * 2 + i;
      int r = c * 16 + srow;
      gload16(&X [(rowA0 + r) * KK + schunk], &Ab[0][c * 512]);
      gload16(&Wb[(rowB0 + r) * KK + schunk], &Bb[0][c * 512]);
    }
  }
  __syncthreads();

  int buf = 0;
  for (int kt = 0; kt < 16; ++kt) {
    if (kt < 15) {
      const int k0 = (kt + 1) * 32;
#pragma unroll
      for (int i = 0; i < 2; ++i) {
        int c = wave * 2 + i;
        int r = c * 16 + srow;
        gload16(&X [(rowA0 + r) * KK + k0 + schunk], &Ab[buf ^ 1][c * 512]);
        gload16(&Wb[(rowB0 + r) * KK + k0 + schunk], &Bb[buf ^ 1][c * 512]);
      }
    }
    // compute on buf
    short8 bfr[4];
#pragma unroll
    for (int ni = 0; ni < 4; ++ni)
      bfr[ni] = *(const short8*)&Bb[buf][(wc * 64 + ni * 16 + lane15) * 32 + rchunk];
#pragma unroll
    for (int mi = 0; mi < 8; ++mi) {
      short8 af = *(const short8*)&Ab[buf][(wr * 128 + mi * 16 + lane15) * 32 + rchunk];
#pragma unroll
      for (int ni = 0; ni < 4; ++ni)
        acc[mi][ni] = __builtin_amdgcn_mfma_f32_16x16x32_bf16(af, bfr[ni], acc[mi][ni], 0, 0, 0);
    }
    if (kt < 15) __syncthreads();   // drains vmcnt (next tile staged) + protects buf reuse
    buf ^= 1;
  }

  // epilogue: bias + store
  int cr = lane >> 4, cc = lane & 15;
#pragma unroll
  for (int ni = 0; ni < 4; ++ni) {
    size_t col = rowB0 + wc * 64 + ni * 16 + cc;
    float bv = bias[col];
#pragma unroll
    for (int mi = 0; mi < 8; ++mi) {
#pragma unroll
      for (int j = 0; j < 4; ++j) {
        size_t rowc = rowA0 + wr * 128 + mi * 16 + cr * 4 + j;
        out[rowc * VOC + col] = acc[mi][ni][j] + bv;
      }
    }
  }
}

extern "C" void kernel_launch(void* const* d_in, const int* in_sizes, int n_in,
                              void* d_out, int out_size, void* d_ws, size_t ws_size,
                              hipStream_t stream) {
  const int* x      = (const int*)d_in[0];
  const float* emb  = (const float*)d_in[1];
  const float* qrot = (const float*)d_in[2];
  const float* krot = (const float*)d_in[3];
  const float* vrot = (const float*)d_in[4];
  const float* ffr  = (const float*)d_in[5];
  const float* ffi  = (const float*)d_in[6];
  const float* wr   = (const float*)d_in[7];
  const float* br   = (const float*)d_in[8];
  const float* wi   = (const float*)d_in[9];
  const float* bi   = (const float*)d_in[10];
  float* out = (float*)d_out;
  char* ws = (char*)d_ws;

  unsigned short* Wb = (unsigned short*)ws;                 // 32,768,000 B
  float* bias = (float*)(ws + 32768000);                    //    128,000 B
  float* Sb = (float*)(ws + 32896000);
  float* Qb = Sb + (size_t)ROWS * KK;
  float* Kb = Qb + (size_t)ROWS * KK;
  float* Vb = Kb + (size_t)ROWS * KK;
  float* S2 = Vb + (size_t)ROWS * KK;
  unsigned short* X = (unsigned short*)(S2 + (size_t)ROWS * KK);

  k_prep<<<dim3(VOC * 128 / 256), dim3(256), 0, stream>>>(wr, wi, br, bi, Wb, bias);
  k_embed<<<dim3(ROWS), dim3(256), 0, stream>>>(x, emb, qrot, krot, vrot, Sb, Qb, Kb, Vb);
  k_attn<<<dim3(ROWS), dim3(256), 0, stream>>>(Qb, Kb, Vb, Sb, S2);
  k_ffnorm<<<dim3(ROWS / 4), dim3(256), 0, stream>>>(S2, ffr, ffi, X);
  k_gemm<<<dim3(2000), dim3(512), 0, stream>>>(X, Wb, bias, out);
}

// Round 4
// 522.618 us; speedup vs baseline: 1.0416x; 1.0416x over previous
//
#include <hip/hip_runtime.h>

// Problem constants
#define DD   256
#define SEQ  128
#define NB   32
#define VOC  32000
#define ROWS (NB * SEQ)   // 4096
#define KK   512          // 2*D (real|imag concat)

typedef __attribute__((ext_vector_type(8))) short short8;
typedef __attribute__((ext_vector_type(4))) float f32x4;

__device__ inline unsigned short f2bf(float f) {
  unsigned int u = __float_as_uint(f);
  u += 0x7FFF + ((u >> 16) & 1);   // RNE
  return (unsigned short)(u >> 16);
}

__device__ inline void gload16(const void* g, void* l) {
  __builtin_amdgcn_global_load_lds(
      (const __attribute__((address_space(1))) void*)g,
      (__attribute__((address_space(3))) void*)l, 16, 0, 0);
}

// K0: pack W rows = [wr | wi] -> bf16, bias = br + bi
__global__ __launch_bounds__(256) void k_prep(
    const float* __restrict__ wr, const float* __restrict__ wi,
    const float* __restrict__ br, const float* __restrict__ bi,
    unsigned short* __restrict__ Wb, float* __restrict__ bias) {
  int idx = blockIdx.x * 256 + threadIdx.x;   // one 4-elem chunk
  int v = idx >> 7, c = idx & 127;
  const float* src = (c < 64) ? (wr + (size_t)v * DD + c * 4)
                              : (wi + (size_t)v * DD + (c - 64) * 4);
  float4 f = *(const float4*)src;
  ushort4 o;
  o.x = f2bf(f.x); o.y = f2bf(f.y); o.z = f2bf(f.z); o.w = f2bf(f.w);
  *(ushort4*)(Wb + (size_t)v * KK + c * 4) = o;
  if (c == 0) bias[v] = br[v] + bi[v];
}

// K1: mag = tanh(emb[x]); state/q/k/v real+imag parts (rot by constant phase)
__global__ __launch_bounds__(256) void k_embed(
    const int* __restrict__ x, const float* __restrict__ emb,
    const float* __restrict__ qrot, const float* __restrict__ krot,
    const float* __restrict__ vrot,
    float* __restrict__ Sb, float* __restrict__ Qb,
    float* __restrict__ Kb, float* __restrict__ Vb) {
  int row = blockIdx.x;          // b*SEQ + s
  int s = row & (SEQ - 1);
  int d = threadIdx.x;
  int tok = x[row];
  float m = tanhf(emb[(size_t)tok * DD + d]);
  float freq = expf(-(float)d * (9.210340371976184f / 256.f)); // 10000^(-d/256)
  float p = (float)s * freq * 3.14159265358979f;
  float sn, cs;
  size_t base = (size_t)row * KK + d;
  sincosf(p, &sn, &cs);             Sb[base] = m * cs; Sb[base + DD] = m * sn;
  float a;
  a = p + qrot[d]; sincosf(a, &sn, &cs); Qb[base] = m * cs; Qb[base + DD] = m * sn;
  a = p + krot[d]; sincosf(a, &sn, &cs); Kb[base] = m * cs; Kb[base + DD] = m * sn;
  a = p + vrot[d]; sincosf(a, &sn, &cs); Vb[base] = m * cs; Vb[base + DD] = m * sn;
}

// K2: one block per (b,s): causal logits (dot*0.5), softmax, PV, residual add
__global__ __launch_bounds__(256) void k_attn(
    const float* __restrict__ Qb, const float* __restrict__ Kb,
    const float* __restrict__ Vb, const float* __restrict__ Sb,
    float* __restrict__ S2) {
  int row = blockIdx.x;
  int b = row >> 7, s = row & 127;
  int tid = threadIdx.x;
  __shared__ __align__(16) float q[KK];
  __shared__ float w[SEQ];
  __shared__ float smax, ssum;
  q[tid] = Qb[(size_t)row * KK + tid];
  q[tid + 256] = Qb[(size_t)row * KK + 256 + tid];
  __syncthreads();
  int t = tid >> 1, half = tid & 1;
  const float4* q4 = (const float4*)(q + half * 256);
  const float4* k4 = (const float4*)(Kb + ((size_t)(b * SEQ + t)) * KK + half * 256);
  float acc = 0.f;
  if (t <= s) {
#pragma unroll 4
    for (int i = 0; i < 64; ++i) {
      float4 qa = q4[i], ka = k4[i];
      acc += qa.x * ka.x + qa.y * ka.y + qa.z * ka.z + qa.w * ka.w;
    }
  }
  acc += __shfl_xor(acc, 1);
  if (half == 0) w[t] = (t <= s) ? acc * 0.5f : -INFINITY;
  __syncthreads();
  if (tid < 64) {
    float m2 = fmaxf(w[tid], w[tid + 64]);
    for (int o = 32; o; o >>= 1) m2 = fmaxf(m2, __shfl_xor(m2, o));
    if (tid == 0) smax = m2;
  }
  __syncthreads();
  if (tid < 128) w[tid] = expf(w[tid] - smax);
  __syncthreads();
  if (tid < 64) {
    float s2 = w[tid] + w[tid + 64];
    for (int o = 32; o; o >>= 1) s2 += __shfl_xor(s2, o);
    if (tid == 0) ssum = s2;
  }
  __syncthreads();
  float inv = 1.f / ssum;
  float o0 = 0.f, o1 = 0.f;
  const float* vb = Vb + (size_t)(b * SEQ) * KK;
  int nt = s + 1;
  for (int tt = 0; tt < nt; ++tt) {
    float wt = w[tt];
    o0 += wt * vb[(size_t)tt * KK + tid];
    o1 += wt * vb[(size_t)tt * KK + 256 + tid];
  }
  size_t base = (size_t)row * KK + tid;
  S2[base] = Sb[base] + o0 * inv;
  S2[base + 256] = Sb[base + 256] + o1 * inv;
}

// K3: complex FF (state @ (ffr + i*ffi)), complex_norm, cast to bf16 X
__global__ __launch_bounds__(256) void k_ffnorm(
    const float* __restrict__ S2, const float* __restrict__ ffr,
    const float* __restrict__ ffi, unsigned short* __restrict__ X) {
  int row0 = blockIdx.x * 4;
  int d = threadIdx.x;
  __shared__ __align__(16) float in[4][KK];
  __shared__ float mg[4][DD];
  __shared__ float stats[8];
#pragma unroll
  for (int i = 0; i < 8; ++i)
    ((float*)in)[i * 256 + d] = S2[(size_t)row0 * KK + i * 256 + d];
  __syncthreads();
  float nr[4] = {0, 0, 0, 0}, ni[4] = {0, 0, 0, 0};
  for (int e = 0; e < DD; ++e) {
    float fr = ffr[e * DD + d];
    float fi = ffi[e * DD + d];
#pragma unroll
    for (int r = 0; r < 4; ++r) {
      float a = in[r][e], c = in[r][DD + e];
      nr[r] += a * fr - c * fi;
      ni[r] += a * fi + c * fr;
    }
  }
#pragma unroll
  for (int r = 0; r < 4; ++r) mg[r][d] = sqrtf(nr[r] * nr[r] + ni[r] * ni[r]);
  __syncthreads();
  int wv = d >> 6, ln = d & 63;
  float s0 = mg[wv][ln] + mg[wv][ln + 64] + mg[wv][ln + 128] + mg[wv][ln + 192];
  for (int o = 32; o; o >>= 1) s0 += __shfl_xor(s0, o);
  float mean = s0 * (1.f / 256.f);
  float var = 0.f;
#pragma unroll
  for (int k = 0; k < 4; ++k) { float t2 = mg[wv][ln + k * 64] - mean; var += t2 * t2; }
  for (int o = 32; o; o >>= 1) var += __shfl_xor(var, o);
  if (ln == 0) { stats[wv * 2] = mean; stats[wv * 2 + 1] = sqrtf(var * (1.f / 255.f)); }
  __syncthreads();
#pragma unroll
  for (int r = 0; r < 4; ++r) {
    float mean2 = stats[r * 2], stdv = stats[r * 2 + 1];
    float mag = mg[r][d];
    float norm = (mag - mean2) / (stdv + 1e-5f);
    float sc = tanhf(norm) / (mag + 1e-5f);
    size_t base = (size_t)(row0 + r) * KK + d;
    X[base] = f2bf(nr[r] * sc);
    X[base + DD] = f2bf(ni[r] * sc);
  }
}

// K4: logits[4096][32000] = X[4096][512] * Wb[32000][512]^T + bias
// 256x256 tile, BK=64, 8 waves (2Mx4N), 128KB LDS ping-pong,
// counted-vmcnt pipeline (T4): steady-state vmcnt(8), never drain-0.
// XOR swizzle chunk^=(row&7) (G4) applied source-side + read-side (rule #21).
#define BK 64
__global__ __launch_bounds__(512, 2) void k_gemm(
    const unsigned short* __restrict__ X, const unsigned short* __restrict__ Wb,
    const float* __restrict__ bias, float* __restrict__ out) {
  __shared__ __align__(16) unsigned short Ab[2][256 * BK];  // 2 x 32 KB
  __shared__ __align__(16) unsigned short Bb[2][256 * BK];  // 2 x 32 KB
  int tid = threadIdx.x;
  int lane = tid & 63, wave = tid >> 6;
  int wr = wave >> 2, wc = wave & 3;          // 2 x 4 wave grid
  // XCD-aware bijective swizzle: 2000 blocks = 8 XCDs x 250 (2000%8==0)
  int orig = blockIdx.x;
  int wg = (orig & 7) * 250 + (orig >> 3);
  int mt = wg & 15, nt = wg >> 4;             // mt fast within XCD chunk
  size_t rowA0 = (size_t)mt * 256;
  size_t rowB0 = (size_t)nt * 256;

  // staging: per wave-load = 8 rows x 8 chunks(16B). lane l -> row base+(l>>3),
  // LDS dest chunk l&7 (linear, HW: base+lane*16). Source chunk = (l&7)^(row&7).
  int srow = lane >> 3;
  int schunk = ((lane & 7) ^ (srow & 7)) * 8;   // elems; row&7 == (l>>3)&7

  f32x4 acc[8][4] = {};

#define STAGE(t, b)                                                          \
  {                                                                          \
    const int k0 = (t) * BK;                                                 \
    _Pragma("unroll")                                                        \
    for (int j = 0; j < 4; ++j) {                                            \
      int rbase = wave * 32 + j * 8;                                         \
      gload16(&X [(rowA0 + rbase + srow) * KK + k0 + schunk],                \
              &Ab[b][rbase * BK]);                                           \
      gload16(&Wb[(rowB0 + rbase + srow) * KK + k0 + schunk],                \
              &Bb[b][rbase * BK]);                                           \
    }                                                                        \
  }

  // prologue: stage tiles 0 and 1 (16 loads/wave), wait for tile 0 only
  STAGE(0, 0);
  STAGE(1, 1);
  asm volatile("s_waitcnt vmcnt(8)" ::: "memory");
  __builtin_amdgcn_s_barrier();
  asm volatile("" ::: "memory");

  int l15 = lane & 15, hi = lane >> 4;
  int buf = 0;
  for (int t = 0; t < 8; ++t) {
    // compute tile t from Ab[buf]/Bb[buf]
#pragma unroll
    for (int ks = 0; ks < 2; ++ks) {
      int cXor = (ks * 4 + hi) ^ (l15 & 7);   // swizzled 16B-chunk index
      short8 bfr[4];
#pragma unroll
      for (int ni = 0; ni < 4; ++ni)
        bfr[ni] = *(const short8*)&Bb[buf][(wc * 64 + ni * 16 + l15) * BK + cXor * 8];
#pragma unroll
      for (int mi = 0; mi < 8; ++mi) {
        short8 af = *(const short8*)&Ab[buf][(wr * 128 + mi * 16 + l15) * BK + cXor * 8];
#pragma unroll
        for (int ni = 0; ni < 4; ++ni)
          acc[mi][ni] = __builtin_amdgcn_mfma_f32_16x16x32_bf16(af, bfr[ni], acc[mi][ni], 0, 0, 0);
      }
    }
    if (t == 7) break;
    // barrier 1: all waves finished reading buf -> safe to overwrite
    asm volatile("" ::: "memory");
    __builtin_amdgcn_s_barrier();
    asm volatile("" ::: "memory");
    if (t < 6) {
      STAGE(t + 2, buf);                                  // 8 new loads
      asm volatile("s_waitcnt vmcnt(8)" ::: "memory");    // tile t+1's 8 landed
    } else {
      asm volatile("s_waitcnt vmcnt(0)" ::: "memory");    // last tile: drain
    }
    // barrier 2: every wave's tile-(t+1) loads are in LDS
    __builtin_amdgcn_s_barrier();
    asm volatile("" ::: "memory");
    buf ^= 1;
  }
#undef STAGE

  // epilogue: bias + store
  int cr = lane >> 4, cc = lane & 15;
#pragma unroll
  for (int ni = 0; ni < 4; ++ni) {
    size_t col = rowB0 + wc * 64 + ni * 16 + cc;
    float bv = bias[col];
#pragma unroll
    for (int mi = 0; mi < 8; ++mi) {
#pragma unroll
      for (int j = 0; j < 4; ++j) {
        size_t rowc = rowA0 + wr * 128 + mi * 16 + cr * 4 + j;
        out[rowc * VOC + col] = acc[mi][ni][j] + bv;
      }
    }
  }
}

extern "C" void kernel_launch(void* const* d_in, const int* in_sizes, int n_in,
                              void* d_out, int out_size, void* d_ws, size_t ws_size,
                              hipStream_t stream) {
  const int* x      = (const int*)d_in[0];
  const float* emb  = (const float*)d_in[1];
  const float* qrot = (const float*)d_in[2];
  const float* krot = (const float*)d_in[3];
  const float* vrot = (const float*)d_in[4];
  const float* ffr  = (const float*)d_in[5];
  const float* ffi  = (const float*)d_in[6];
  const float* wr   = (const float*)d_in[7];
  const float* br   = (const float*)d_in[8];
  const float* wi   = (const float*)d_in[9];
  const float* bi   = (const float*)d_in[10];
  float* out = (float*)d_out;
  char* ws = (char*)d_ws;

  unsigned short* Wb = (unsigned short*)ws;                 // 32,768,000 B
  float* bias = (float*)(ws + 32768000);                    //    128,000 B
  float* Sb = (float*)(ws + 32896000);
  float* Qb = Sb + (size_t)ROWS * KK;
  float* Kb = Qb + (size_t)ROWS * KK;
  float* Vb = Kb + (size_t)ROWS * KK;
  float* S2 = Vb + (size_t)ROWS * KK;
  unsigned short* X = (unsigned short*)(S2 + (size_t)ROWS * KK);

  k_prep<<<dim3(VOC * 128 / 256), dim3(256), 0, stream>>>(wr, wi, br, bi, Wb, bias);
  k_embed<<<dim3(ROWS), dim3(256), 0, stream>>>(x, emb, qrot, krot, vrot, Sb, Qb, Kb, Vb);
  k_attn<<<dim3(ROWS), dim3(256), 0, stream>>>(Qb, Kb, Vb, Sb, S2);
  k_ffnorm<<<dim3(ROWS / 4), dim3(256), 0, stream>>>(S2, ffr, ffi, X);
  k_gemm<<<dim3(2000), dim3(512), 0, stream>>>(X, Wb, bias, out);
}

// Round 5
// 495.981 us; speedup vs baseline: 1.0975x; 1.0537x over previous
//
#include <hip/hip_runtime.h>

// Problem constants
#define DD   256
#define SEQ  128
#define NB   32
#define VOC  32000
#define ROWS (NB * SEQ)   // 4096
#define KK   512          // 2*D (real|imag concat)

typedef __attribute__((ext_vector_type(8))) short short8;
typedef __attribute__((ext_vector_type(4))) float f32x4;

__device__ inline unsigned short f2bf(float f) {
  unsigned int u = __float_as_uint(f);
  u += 0x7FFF + ((u >> 16) & 1);   // RNE
  return (unsigned short)(u >> 16);
}

__device__ inline void gload16(const void* g, void* l) {
  __builtin_amdgcn_global_load_lds(
      (const __attribute__((address_space(1))) void*)g,
      (__attribute__((address_space(3))) void*)l, 16, 0, 0);
}

// K0: pack W rows = [wr | wi] -> bf16, bias = br + bi, rot sin/cos table
__global__ __launch_bounds__(256) void k_prep(
    const float* __restrict__ wr, const float* __restrict__ wi,
    const float* __restrict__ br, const float* __restrict__ bi,
    const float* __restrict__ qrot, const float* __restrict__ krot,
    const float* __restrict__ vrot,
    unsigned short* __restrict__ Wb, float* __restrict__ bias,
    float* __restrict__ rotcs) {
  int idx = blockIdx.x * 256 + threadIdx.x;   // one 4-elem chunk
  int v = idx >> 7, c = idx & 127;
  const float* src = (c < 64) ? (wr + (size_t)v * DD + c * 4)
                              : (wi + (size_t)v * DD + (c - 64) * 4);
  float4 f = *(const float4*)src;
  ushort4 o;
  o.x = f2bf(f.x); o.y = f2bf(f.y); o.z = f2bf(f.z); o.w = f2bf(f.w);
  *(ushort4*)(Wb + (size_t)v * KK + c * 4) = o;
  if (c == 0) bias[v] = br[v] + bi[v];
  if (idx < DD) {
    float s0, c0;
    sincosf(qrot[idx], &s0, &c0); rotcs[idx] = c0;          rotcs[DD + idx] = s0;
    sincosf(krot[idx], &s0, &c0); rotcs[2 * DD + idx] = c0; rotcs[3 * DD + idx] = s0;
    sincosf(vrot[idx], &s0, &c0); rotcs[4 * DD + idx] = c0; rotcs[5 * DD + idx] = s0;
  }
}

// K1: mag = tanh(emb[x]); state/q/k/v via one sincos + angle addition
__global__ __launch_bounds__(256) void k_embed(
    const int* __restrict__ x, const float* __restrict__ emb,
    const float* __restrict__ rotcs,
    float* __restrict__ Sb, float* __restrict__ Qb,
    float* __restrict__ Kb, float* __restrict__ Vb) {
  int row = blockIdx.x;          // b*SEQ + s
  int s = row & (SEQ - 1);
  int d = threadIdx.x;
  int tok = x[row];
  float m = tanhf(emb[(size_t)tok * DD + d]);
  float freq = __expf(-(float)d * (9.210340371976184f / 256.f)); // 10000^(-d/256)
  float p = (float)s * freq * 3.14159265358979f;
  float sp, cp;
  __sincosf(p, &sp, &cp);
  size_t base = (size_t)row * KK + d;
  Sb[base] = m * cp; Sb[base + DD] = m * sp;
  float cr, sr;
  cr = rotcs[d];          sr = rotcs[DD + d];
  Qb[base] = m * (cp * cr - sp * sr); Qb[base + DD] = m * (sp * cr + cp * sr);
  cr = rotcs[2 * DD + d]; sr = rotcs[3 * DD + d];
  Kb[base] = m * (cp * cr - sp * sr); Kb[base + DD] = m * (sp * cr + cp * sr);
  cr = rotcs[4 * DD + d]; sr = rotcs[5 * DD + d];
  Vb[base] = m * (cp * cr - sp * sr); Vb[base + DD] = m * (sp * cr + cp * sr);
}

// K2: one block per (b,s): causal logits (dot*0.5), softmax, PV, residual add
__global__ __launch_bounds__(256) void k_attn(
    const float* __restrict__ Qb, const float* __restrict__ Kb,
    const float* __restrict__ Vb, const float* __restrict__ Sb,
    float* __restrict__ S2) {
  int row = blockIdx.x;
  int b = row >> 7, s = row & 127;
  int tid = threadIdx.x;
  __shared__ __align__(16) float q[KK];
  __shared__ float w[SEQ];
  __shared__ float smax, ssum;
  q[tid] = Qb[(size_t)row * KK + tid];
  q[tid + 256] = Qb[(size_t)row * KK + 256 + tid];
  __syncthreads();
  int t = tid >> 1, half = tid & 1;
  const float4* q4 = (const float4*)(q + half * 256);
  const float4* k4 = (const float4*)(Kb + ((size_t)(b * SEQ + t)) * KK + half * 256);
  float a0 = 0.f, a1 = 0.f, a2 = 0.f, a3 = 0.f;
  if (t <= s) {
#pragma unroll 4
    for (int i = 0; i < 64; ++i) {
      float4 qa = q4[i], ka = k4[i];
      a0 += qa.x * ka.x; a1 += qa.y * ka.y; a2 += qa.z * ka.z; a3 += qa.w * ka.w;
    }
  }
  float acc = (a0 + a1) + (a2 + a3);
  acc += __shfl_xor(acc, 1);
  if (half == 0) w[t] = (t <= s) ? acc * 0.5f : -INFINITY;
  __syncthreads();
  if (tid < 64) {
    float m2 = fmaxf(w[tid], w[tid + 64]);
    for (int o = 32; o; o >>= 1) m2 = fmaxf(m2, __shfl_xor(m2, o));
    if (tid == 0) smax = m2;
  }
  __syncthreads();
  if (tid < 128) w[tid] = expf(w[tid] - smax);
  __syncthreads();
  if (tid < 64) {
    float s2 = w[tid] + w[tid + 64];
    for (int o = 32; o; o >>= 1) s2 += __shfl_xor(s2, o);
    if (tid == 0) ssum = s2;
  }
  __syncthreads();
  float inv = 1.f / ssum;
  float o0a = 0.f, o0b = 0.f, o1a = 0.f, o1b = 0.f;
  const float* vb = Vb + (size_t)(b * SEQ) * KK;
  int nt = s + 1;
  for (int tt = 0; tt + 1 < nt; tt += 2) {
    float w0 = w[tt], w1 = w[tt + 1];
    o0a += w0 * vb[(size_t)tt * KK + tid];
    o1a += w0 * vb[(size_t)tt * KK + 256 + tid];
    o0b += w1 * vb[(size_t)(tt + 1) * KK + tid];
    o1b += w1 * vb[(size_t)(tt + 1) * KK + 256 + tid];
  }
  if (nt & 1) {
    int tt = nt - 1;
    float w0 = w[tt];
    o0a += w0 * vb[(size_t)tt * KK + tid];
    o1a += w0 * vb[(size_t)tt * KK + 256 + tid];
  }
  size_t base = (size_t)row * KK + tid;
  S2[base] = Sb[base] + (o0a + o0b) * inv;
  S2[base + 256] = Sb[base + 256] + (o1a + o1b) * inv;
}

// K3: complex FF (state @ (ffr + i*ffi)), complex_norm, cast to bf16 X
__global__ __launch_bounds__(256) void k_ffnorm(
    const float* __restrict__ S2, const float* __restrict__ ffr,
    const float* __restrict__ ffi, unsigned short* __restrict__ X) {
  int row0 = blockIdx.x * 4;
  int d = threadIdx.x;
  __shared__ __align__(16) float in[4][KK];
  __shared__ float mg[4][DD];
  __shared__ float stats[8];
#pragma unroll
  for (int i = 0; i < 8; ++i)
    ((float*)in)[i * 256 + d] = S2[(size_t)row0 * KK + i * 256 + d];
  __syncthreads();
  float nr[4] = {0, 0, 0, 0}, ni[4] = {0, 0, 0, 0};
  for (int e = 0; e < DD; ++e) {
    float fr = ffr[e * DD + d];
    float fi = ffi[e * DD + d];
#pragma unroll
    for (int r = 0; r < 4; ++r) {
      float a = in[r][e], c = in[r][DD + e];
      nr[r] += a * fr - c * fi;
      ni[r] += a * fi + c * fr;
    }
  }
#pragma unroll
  for (int r = 0; r < 4; ++r) mg[r][d] = sqrtf(nr[r] * nr[r] + ni[r] * ni[r]);
  __syncthreads();
  int wv = d >> 6, ln = d & 63;
  float s0 = mg[wv][ln] + mg[wv][ln + 64] + mg[wv][ln + 128] + mg[wv][ln + 192];
  for (int o = 32; o; o >>= 1) s0 += __shfl_xor(s0, o);
  float mean = s0 * (1.f / 256.f);
  float var = 0.f;
#pragma unroll
  for (int k = 0; k < 4; ++k) { float t2 = mg[wv][ln + k * 64] - mean; var += t2 * t2; }
  for (int o = 32; o; o >>= 1) var += __shfl_xor(var, o);
  if (ln == 0) { stats[wv * 2] = mean; stats[wv * 2 + 1] = sqrtf(var * (1.f / 255.f)); }
  __syncthreads();
#pragma unroll
  for (int r = 0; r < 4; ++r) {
    float mean2 = stats[r * 2], stdv = stats[r * 2 + 1];
    float mag = mg[r][d];
    float norm = (mag - mean2) / (stdv + 1e-5f);
    float sc = tanhf(norm) / (mag + 1e-5f);
    size_t base = (size_t)(row0 + r) * KK + d;
    X[base] = f2bf(nr[r] * sc);
    X[base + DD] = f2bf(ni[r] * sc);
  }
}

// K4: logits = X[4096][512] * Wb[32000][512]^T + bias
// 256x256 tile, BK=32, 8 waves (2Mx4N), 4 LDS buffers (128KB),
// phase-split pipeline (T3): 2 phases/tile, 16 MFMA each, setprio (T5),
// counted vmcnt(8) depth-3 prefetch (T4), source-side XOR swizzle (rule #21),
// XCD-aware bijective block swizzle (T1).
__global__ __launch_bounds__(512, 2) void k_gemm(
    const unsigned short* __restrict__ X, const unsigned short* __restrict__ Wb,
    const float* __restrict__ bias, float* __restrict__ out) {
  __shared__ __align__(16) unsigned short Ab[4][256 * 32];  // 4 x 16 KB
  __shared__ __align__(16) unsigned short Bb[4][256 * 32];  // 4 x 16 KB
  int tid = threadIdx.x;
  int lane = tid & 63, wave = tid >> 6;
  int wr = wave >> 2, wc = wave & 3;          // 2 x 4 wave grid
  // XCD-aware bijective swizzle: 2000 blocks = 8 XCDs x 250
  int orig = blockIdx.x;
  int wg = (orig & 7) * 250 + (orig >> 3);
  int mt = wg & 15, nt = wg >> 4;
  size_t rowA0 = (size_t)mt * 256;
  size_t rowB0 = (size_t)nt * 256;

  // staging: wave-load = 16 rows x 64B (1KB). lane l -> row l>>2, LDS chunk l&3
  // (linear dest). Source chunk = (l&3) ^ (row&3)  [involution]
  int srow = lane >> 2;
  int schunk = ((lane & 3) ^ (srow & 3)) * 8;   // elems

  f32x4 acc[8][4] = {};

#define STAGE_A(t, b)                                                        \
  { const int k0 = (t) * 32;                                                 \
    _Pragma("unroll")                                                        \
    for (int j = 0; j < 2; ++j) {                                            \
      int rbase = wave * 32 + j * 16;                                        \
      gload16(&X[(rowA0 + rbase + srow) * KK + k0 + schunk],                 \
              &Ab[b][rbase * 32]); } }
#define STAGE_B(t, b)                                                        \
  { const int k0 = (t) * 32;                                                 \
    _Pragma("unroll")                                                        \
    for (int j = 0; j < 2; ++j) {                                            \
      int rbase = wave * 32 + j * 16;                                        \
      gload16(&Wb[(rowB0 + rbase + srow) * KK + k0 + schunk],                \
              &Bb[b][rbase * 32]); } }

  // prologue: stage tiles 0,1,2 (12 loads/wave); wait tile 0 (leave 8 in flight)
  STAGE_A(0, 0); STAGE_B(0, 0);
  STAGE_A(1, 1); STAGE_B(1, 1);
  STAGE_A(2, 2); STAGE_B(2, 2);
  asm volatile("s_waitcnt vmcnt(8)" ::: "memory");
  __builtin_amdgcn_s_barrier();

  int l15 = lane & 15, hi = lane >> 4;
  int rch = (hi ^ (l15 & 3)) * 8;   // swizzled read chunk (elems)

  for (int t = 0; t < 16; ++t) {
    const unsigned short* Abuf = &Ab[t & 3][0];
    const unsigned short* Bbuf = &Bb[t & 3][0];
    // ---- P0: read B frags + A lo-half frags; stage A of t+3 ----
    short8 bfr[4], af0[4];
#pragma unroll
    for (int ni = 0; ni < 4; ++ni)
      bfr[ni] = *(const short8*)&Bbuf[(wc * 64 + ni * 16 + l15) * 32 + rch];
#pragma unroll
    for (int mi = 0; mi < 4; ++mi)
      af0[mi] = *(const short8*)&Abuf[(wr * 128 + mi * 16 + l15) * 32 + rch];
    if (t < 13) STAGE_A(t + 3, (t + 3) & 3);
    asm volatile("" ::: "memory");
    __builtin_amdgcn_s_barrier();
    asm volatile("s_waitcnt lgkmcnt(0)" ::: "memory");
    __builtin_amdgcn_sched_barrier(0);
    __builtin_amdgcn_s_setprio(1);
#pragma unroll
    for (int mi = 0; mi < 4; ++mi)
#pragma unroll
      for (int ni = 0; ni < 4; ++ni)
        acc[mi][ni] = __builtin_amdgcn_mfma_f32_16x16x32_bf16(af0[mi], bfr[ni], acc[mi][ni], 0, 0, 0);
    __builtin_amdgcn_s_setprio(0);
    asm volatile("" ::: "memory");
    __builtin_amdgcn_s_barrier();
    // ---- P1: read A hi-half frags; stage B of t+3 ----
    short8 af1[4];
#pragma unroll
    for (int mi = 0; mi < 4; ++mi)
      af1[mi] = *(const short8*)&Abuf[(wr * 128 + (mi + 4) * 16 + l15) * 32 + rch];
    if (t < 13) STAGE_B(t + 3, (t + 3) & 3);
    asm volatile("" ::: "memory");
    __builtin_amdgcn_s_barrier();
    asm volatile("s_waitcnt lgkmcnt(0)" ::: "memory");
    __builtin_amdgcn_sched_barrier(0);
    __builtin_amdgcn_s_setprio(1);
#pragma unroll
    for (int mi = 0; mi < 4; ++mi)
#pragma unroll
      for (int ni = 0; ni < 4; ++ni)
        acc[mi + 4][ni] = __builtin_amdgcn_mfma_f32_16x16x32_bf16(af1[mi], bfr[ni], acc[mi + 4][ni], 0, 0, 0);
    __builtin_amdgcn_s_setprio(0);
    // ---- end of tile: ensure tile t+1 visible; keep t+2,t+3 in flight ----
    if (t < 15) {
      if (t <= 12)      asm volatile("s_waitcnt vmcnt(8)" ::: "memory");
      else if (t == 13) asm volatile("s_waitcnt vmcnt(4)" ::: "memory");
      else              asm volatile("s_waitcnt vmcnt(0)" ::: "memory");
      __builtin_amdgcn_s_barrier();
    }
  }
#undef STAGE_A
#undef STAGE_B

  // epilogue: bias + store
  int cr = lane >> 4, cc = lane & 15;
#pragma unroll
  for (int ni = 0; ni < 4; ++ni) {
    size_t col = rowB0 + wc * 64 + ni * 16 + cc;
    float bv = bias[col];
#pragma unroll
    for (int mi = 0; mi < 8; ++mi) {
#pragma unroll
      for (int j = 0; j < 4; ++j) {
        size_t rowc = rowA0 + wr * 128 + mi * 16 + cr * 4 + j;
        out[rowc * VOC + col] = acc[mi][ni][j] + bv;
      }
    }
  }
}

extern "C" void kernel_launch(void* const* d_in, const int* in_sizes, int n_in,
                              void* d_out, int out_size, void* d_ws, size_t ws_size,
                              hipStream_t stream) {
  const int* x      = (const int*)d_in[0];
  const float* emb  = (const float*)d_in[1];
  const float* qrot = (const float*)d_in[2];
  const float* krot = (const float*)d_in[3];
  const float* vrot = (const float*)d_in[4];
  const float* ffr  = (const float*)d_in[5];
  const float* ffi  = (const float*)d_in[6];
  const float* wr   = (const float*)d_in[7];
  const float* br   = (const float*)d_in[8];
  const float* wi   = (const float*)d_in[9];
  const float* bi   = (const float*)d_in[10];
  float* out = (float*)d_out;
  char* ws = (char*)d_ws;

  unsigned short* Wb = (unsigned short*)ws;                 // 32,768,000 B
  float* bias = (float*)(ws + 32768000);                    //    128,000 B
  float* Sb = (float*)(ws + 32896000);
  float* Qb = Sb + (size_t)ROWS * KK;
  float* Kb = Qb + (size_t)ROWS * KK;
  float* Vb = Kb + (size_t)ROWS * KK;
  float* S2 = Vb + (size_t)ROWS * KK;
  unsigned short* Xb = (unsigned short*)(S2 + (size_t)ROWS * KK);
  float* rotcs = S2;   // 6*256 floats scratch; k_embed reads before k_attn writes S2

  k_prep<<<dim3(VOC * 128 / 256), dim3(256), 0, stream>>>(wr, wi, br, bi, qrot, krot, vrot, Wb, bias, rotcs);
  k_embed<<<dim3(ROWS), dim3(256), 0, stream>>>(x, emb, rotcs, Sb, Qb, Kb, Vb);
  k_attn<<<dim3(ROWS), dim3(256), 0, stream>>>(Qb, Kb, Vb, Sb, S2);
  k_ffnorm<<<dim3(ROWS / 4), dim3(256), 0, stream>>>(S2, ffr, ffi, Xb);
  k_gemm<<<dim3(2000), dim3(512), 0, stream>>>(Xb, Wb, bias, out);
}

// Round 6
// 330.835 us; speedup vs baseline: 1.6454x; 1.4992x over previous
//
#include <hip/hip_runtime.h>

// Problem constants
#define DD   256
#define SEQ  128
#define NB   32
#define VOC  32000
#define ROWS (NB * SEQ)   // 4096
#define KK   512          // 2*D (real|imag concat)

typedef __attribute__((ext_vector_type(8))) short short8;
typedef __attribute__((ext_vector_type(4))) float f32x4;

__device__ inline unsigned short f2bf(float f) {
  unsigned int u = __float_as_uint(f);
  u += 0x7FFF + ((u >> 16) & 1);   // RNE
  return (unsigned short)(u >> 16);
}

__device__ inline void gload16(const void* g, void* l) {
  __builtin_amdgcn_global_load_lds(
      (const __attribute__((address_space(1))) void*)g,
      (__attribute__((address_space(3))) void*)l, 16, 0, 0);
}

// K0: pack W rows = [wr | wi] -> bf16, bias = br + bi, rot sin/cos table
__global__ __launch_bounds__(256) void k_prep(
    const float* __restrict__ wr, const float* __restrict__ wi,
    const float* __restrict__ br, const float* __restrict__ bi,
    const float* __restrict__ qrot, const float* __restrict__ krot,
    const float* __restrict__ vrot,
    unsigned short* __restrict__ Wb, float* __restrict__ bias,
    float* __restrict__ rotcs) {
  int idx = blockIdx.x * 256 + threadIdx.x;   // one 4-elem chunk
  int v = idx >> 7, c = idx & 127;
  const float* src = (c < 64) ? (wr + (size_t)v * DD + c * 4)
                              : (wi + (size_t)v * DD + (c - 64) * 4);
  float4 f = *(const float4*)src;
  ushort4 o;
  o.x = f2bf(f.x); o.y = f2bf(f.y); o.z = f2bf(f.z); o.w = f2bf(f.w);
  *(ushort4*)(Wb + (size_t)v * KK + c * 4) = o;
  if (c == 0) bias[v] = br[v] + bi[v];
  if (idx < DD) {
    float s0, c0;
    sincosf(qrot[idx], &s0, &c0); rotcs[idx] = c0;          rotcs[DD + idx] = s0;
    sincosf(krot[idx], &s0, &c0); rotcs[2 * DD + idx] = c0; rotcs[3 * DD + idx] = s0;
    sincosf(vrot[idx], &s0, &c0); rotcs[4 * DD + idx] = c0; rotcs[5 * DD + idx] = s0;
  }
}

// K1: mag = tanh(emb[x]); state/q/k/v via one sincos + angle addition
__global__ __launch_bounds__(256) void k_embed(
    const int* __restrict__ x, const float* __restrict__ emb,
    const float* __restrict__ rotcs,
    float* __restrict__ Sb, float* __restrict__ Qb,
    float* __restrict__ Kb, float* __restrict__ Vb) {
  int row = blockIdx.x;          // b*SEQ + s
  int s = row & (SEQ - 1);
  int d = threadIdx.x;
  int tok = x[row];
  float m = tanhf(emb[(size_t)tok * DD + d]);
  float freq = __expf(-(float)d * (9.210340371976184f / 256.f)); // 10000^(-d/256)
  float p = (float)s * freq * 3.14159265358979f;
  float sp, cp;
  __sincosf(p, &sp, &cp);
  size_t base = (size_t)row * KK + d;
  Sb[base] = m * cp; Sb[base + DD] = m * sp;
  float cr, sr;
  cr = rotcs[d];          sr = rotcs[DD + d];
  Qb[base] = m * (cp * cr - sp * sr); Qb[base + DD] = m * (sp * cr + cp * sr);
  cr = rotcs[2 * DD + d]; sr = rotcs[3 * DD + d];
  Kb[base] = m * (cp * cr - sp * sr); Kb[base + DD] = m * (sp * cr + cp * sr);
  cr = rotcs[4 * DD + d]; sr = rotcs[5 * DD + d];
  Vb[base] = m * (cp * cr - sp * sr); Vb[base + DD] = m * (sp * cr + cp * sr);
}

// K2: one block per (batch, 16-query group). 512 threads.
// thread = (q = tid>>5, tt = (tid&31)&15, half = (tid&31)>>4)
#define QBLK 16
#define QPAD (KK + 4)
__global__ __launch_bounds__(512) void k_attn(
    const float* __restrict__ Qb, const float* __restrict__ Kb,
    const float* __restrict__ Vb, const float* __restrict__ Sb,
    float* __restrict__ S2) {
  int blk = blockIdx.x;
  int b = blk >> 3, g = blk & 7;
  int tid = threadIdx.x;
  int q = tid >> 5, t5 = tid & 31;
  int tt = t5 & 15, half = t5 >> 4;
  __shared__ __align__(16) float Ql[QBLK][QPAD];
  __shared__ __align__(16) float KVl[QBLK][QPAD];
  __shared__ float w[QBLK][SEQ];
  size_t qrow0 = (size_t)b * SEQ + g * QBLK;
  const float* qsrc = Qb + qrow0 * KK;
#pragma unroll
  for (int i = 0; i < 4; ++i) {           // 2048 float4 / 512 threads
    int idx = i * 512 + tid;
    int r = idx >> 7, c = idx & 127;
    *(float4*)&Ql[r][c * 4] = *(const float4*)&qsrc[(size_t)r * KK + c * 4];
  }
  int ntile = g + 1;
  int srow = g * QBLK + q;
  // ---- phase A: logits ----
  for (int kt = 0; kt < ntile; ++kt) {
    __syncthreads();                      // prev KVl reads done (and Q staged, kt=0)
    const float* ksrc = Kb + ((size_t)b * SEQ + kt * QBLK) * KK;
#pragma unroll
    for (int i = 0; i < 4; ++i) {
      int idx = i * 512 + tid;
      int r = idx >> 7, c = idx & 127;
      *(float4*)&KVl[r][c * 4] = *(const float4*)&ksrc[(size_t)r * KK + c * 4];
    }
    __syncthreads();
    const float4* qrow = (const float4*)&Ql[q][half * 256];
    const float4* krow = (const float4*)&KVl[tt][half * 256];
    float a0 = 0.f, a1 = 0.f, a2 = 0.f, a3 = 0.f;
#pragma unroll 8
    for (int cc = 0; cc < 64; ++cc) {
      float4 qa = qrow[cc], ka = krow[cc];
      a0 += qa.x * ka.x; a1 += qa.y * ka.y; a2 += qa.z * ka.z; a3 += qa.w * ka.w;
    }
    float acc = (a0 + a1) + (a2 + a3);
    acc += __shfl_xor(acc, 16);
    int t = kt * QBLK + tt;
    if (half == 0) w[q][t] = (t <= srow) ? acc * 0.5f : -INFINITY;
  }
  __syncthreads();
  // ---- softmax over w[q][0..nk) (redundant across half) ----
  int nk = ntile * QBLK;
  float mx = -INFINITY;
  for (int t = tt; t < nk; t += 16) mx = fmaxf(mx, w[q][t]);
#pragma unroll
  for (int o = 8; o; o >>= 1) mx = fmaxf(mx, __shfl_xor(mx, o));
  float sm = 0.f;
  for (int t = tt; t < nk; t += 16) {
    float e = __expf(w[q][t] - mx);
    if (half == 0) w[q][t] = e;
    sm += e;
  }
#pragma unroll
  for (int o = 8; o; o >>= 1) sm += __shfl_xor(sm, o);
  float inv = 1.f / sm;
  // ---- phase B: PV ----
  float4 facc[4] = {};
  for (int kt = 0; kt < ntile; ++kt) {
    __syncthreads();                      // logits/PV reads of KVl + w writes visible
    const float* vsrc = Vb + ((size_t)b * SEQ + kt * QBLK) * KK;
#pragma unroll
    for (int i = 0; i < 4; ++i) {
      int idx = i * 512 + tid;
      int r = idx >> 7, c = idx & 127;
      *(float4*)&KVl[r][c * 4] = *(const float4*)&vsrc[(size_t)r * KK + c * 4];
    }
    __syncthreads();
#pragma unroll
    for (int t1 = 0; t1 < QBLK; ++t1) {
      float wv = w[q][kt * QBLK + t1];
#pragma unroll
      for (int j = 0; j < 4; ++j) {
        float4 v4 = *(const float4*)&KVl[t1][tt * 4 + (j + 4 * half) * 64];
        facc[j].x += wv * v4.x; facc[j].y += wv * v4.y;
        facc[j].z += wv * v4.z; facc[j].w += wv * v4.w;
      }
    }
  }
  // ---- epilogue: residual add ----
  const float* ssrc = Sb + (qrow0 + q) * KK;
  float* dst = S2 + (qrow0 + q) * KK;
#pragma unroll
  for (int j = 0; j < 4; ++j) {
    int d0 = tt * 4 + (j + 4 * half) * 64;
    float4 sv = *(const float4*)&ssrc[d0];
    float4 o;
    o.x = sv.x + facc[j].x * inv; o.y = sv.y + facc[j].y * inv;
    o.z = sv.z + facc[j].z * inv; o.w = sv.w + facc[j].w * inv;
    *(float4*)&dst[d0] = o;
  }
}

// K3: complex FF + complex_norm + bf16 cast. 8 rows/block.
__global__ __launch_bounds__(256) void k_ffnorm(
    const float* __restrict__ S2, const float* __restrict__ ffr,
    const float* __restrict__ ffi, unsigned short* __restrict__ X) {
  int row0 = blockIdx.x * 8;
  int d = threadIdx.x;
  __shared__ __align__(16) float in[8][KK];   // 16 KB
  __shared__ float mg[8][DD];                 // 8 KB
  __shared__ float stats[16];
#pragma unroll
  for (int i = 0; i < 4; ++i) {               // 1024 float4 / 256 threads
    int idx = i * 256 + d;
    *(float4*)&((float*)in)[idx * 4] = *(const float4*)&S2[(size_t)row0 * KK + idx * 4];
  }
  __syncthreads();
  float nr[8] = {0,0,0,0,0,0,0,0}, ni[8] = {0,0,0,0,0,0,0,0};
  for (int e4 = 0; e4 < 64; ++e4) {
    int e = e4 * 4;
    float fr0 = ffr[(e+0)*DD + d], fr1 = ffr[(e+1)*DD + d];
    float fr2 = ffr[(e+2)*DD + d], fr3 = ffr[(e+3)*DD + d];
    float fi0 = ffi[(e+0)*DD + d], fi1 = ffi[(e+1)*DD + d];
    float fi2 = ffi[(e+2)*DD + d], fi3 = ffi[(e+3)*DD + d];
#pragma unroll
    for (int r = 0; r < 8; ++r) {
      float4 av = *(const float4*)&in[r][e];
      float4 cv = *(const float4*)&in[r][DD + e];
      nr[r] += av.x*fr0 - cv.x*fi0 + av.y*fr1 - cv.y*fi1
             + av.z*fr2 - cv.z*fi2 + av.w*fr3 - cv.w*fi3;
      ni[r] += av.x*fi0 + cv.x*fr0 + av.y*fi1 + cv.y*fr1
             + av.z*fi2 + cv.z*fr2 + av.w*fi3 + cv.w*fr3;
    }
  }
#pragma unroll
  for (int r = 0; r < 8; ++r) mg[r][d] = sqrtf(nr[r]*nr[r] + ni[r]*ni[r]);
  __syncthreads();
  int wv = d >> 6, ln = d & 63;
#pragma unroll
  for (int k = 0; k < 2; ++k) {
    int r = wv + k * 4;
    float s0 = mg[r][ln] + mg[r][ln+64] + mg[r][ln+128] + mg[r][ln+192];
#pragma unroll
    for (int o = 32; o; o >>= 1) s0 += __shfl_xor(s0, o);
    float mean = s0 * (1.f / 256.f);
    float var = 0.f;
#pragma unroll
    for (int j = 0; j < 4; ++j) { float t2 = mg[r][ln + j*64] - mean; var += t2*t2; }
#pragma unroll
    for (int o = 32; o; o >>= 1) var += __shfl_xor(var, o);
    if (ln == 0) { stats[r*2] = mean; stats[r*2+1] = sqrtf(var * (1.f/255.f)); }
  }
  __syncthreads();
#pragma unroll
  for (int r = 0; r < 8; ++r) {
    float mean2 = stats[r*2], stdv = stats[r*2+1];
    float mag = mg[r][d];
    float norm = (mag - mean2) / (stdv + 1e-5f);
    float sc = tanhf(norm) / (mag + 1e-5f);
    size_t base = (size_t)(row0 + r) * KK + d;
    X[base] = f2bf(nr[r] * sc);
    X[base + DD] = f2bf(ni[r] * sc);
  }
}

// K4: logits = X[4096][512] * Wb[32000][512]^T + bias
// m97 structure: 128x128 tile, BK=64, 4 waves, single 32KB LDS buffer,
// 2-barrier K-loop, global_load_lds w16, XOR swizzle (verified 0-conflict),
// ~3 blocks/CU for cross-block store/compute overlap. Nontemporal C stores.
__global__ __launch_bounds__(256, 3) void k_gemm(
    const unsigned short* __restrict__ X, const unsigned short* __restrict__ Wb,
    const float* __restrict__ bias, float* __restrict__ out) {
  __shared__ __align__(16) unsigned short At[128 * 64];   // 16 KB
  __shared__ __align__(16) unsigned short Bt[128 * 64];   // 16 KB
  int tid = threadIdx.x;
  int lane = tid & 63, wave = tid >> 6;
  int wr = wave >> 1, wc = wave & 1;          // 2 x 2 wave grid (64x64 each)
  // XCD-aware bijective swizzle: 8000 blocks = 8 XCDs x 1000; mt-fast
  int orig = blockIdx.x;
  int wg = (orig & 7) * 1000 + (orig >> 3);
  int mt = wg & 31, nt = wg >> 5;             // 32 M-tiles x 250 N-tiles
  size_t rowA0 = (size_t)mt * 128;
  size_t rowB0 = (size_t)nt * 128;

  // staging: wave pass = 8 rows x 8 chunks(16B). lane l -> row l>>3, LDS chunk l&7
  // (linear dest). Source chunk = (l&7) ^ (row&7)  [involution]
  int srow = lane >> 3;
  int schunk = ((lane & 7) ^ (srow & 7)) * 8;   // elems

  f32x4 acc[4][4] = {};
  int l15 = lane & 15, hi = lane >> 4;

  for (int kt = 0; kt < 8; ++kt) {
    if (kt) { asm volatile("" ::: "memory"); __builtin_amdgcn_s_barrier(); }
    const int k0 = kt * 64;
#pragma unroll
    for (int j = 0; j < 4; ++j) {
      int rbase = wave * 32 + j * 8;
      gload16(&X [(rowA0 + rbase + srow) * KK + k0 + schunk], &At[rbase * 64]);
      gload16(&Wb[(rowB0 + rbase + srow) * KK + k0 + schunk], &Bt[rbase * 64]);
    }
    asm volatile("s_waitcnt vmcnt(0)" ::: "memory");
    __builtin_amdgcn_s_barrier();
    asm volatile("" ::: "memory");
#pragma unroll
    for (int ks = 0; ks < 2; ++ks) {
      int cXor = (ks * 4 + hi) ^ (l15 & 7);   // swizzled 16B-chunk index
      short8 a[4], bb[4];
#pragma unroll
      for (int ni = 0; ni < 4; ++ni)
        bb[ni] = *(const short8*)&Bt[(wc * 64 + ni * 16 + l15) * 64 + cXor * 8];
#pragma unroll
      for (int mi = 0; mi < 4; ++mi)
        a[mi] = *(const short8*)&At[(wr * 64 + mi * 16 + l15) * 64 + cXor * 8];
#pragma unroll
      for (int mi = 0; mi < 4; ++mi)
#pragma unroll
        for (int ni = 0; ni < 4; ++ni)
          acc[mi][ni] = __builtin_amdgcn_mfma_f32_16x16x32_bf16(a[mi], bb[ni], acc[mi][ni], 0, 0, 0);
    }
  }

  // epilogue: bias + nontemporal store
  int cr = lane >> 4, cc = lane & 15;
#pragma unroll
  for (int ni = 0; ni < 4; ++ni) {
    size_t col = rowB0 + wc * 64 + ni * 16 + cc;
    float bv = bias[col];
#pragma unroll
    for (int mi = 0; mi < 4; ++mi) {
#pragma unroll
      for (int j = 0; j < 4; ++j) {
        size_t rowc = rowA0 + wr * 64 + mi * 16 + cr * 4 + j;
        __builtin_nontemporal_store(acc[mi][ni][j] + bv, &out[rowc * VOC + col]);
      }
    }
  }
}

extern "C" void kernel_launch(void* const* d_in, const int* in_sizes, int n_in,
                              void* d_out, int out_size, void* d_ws, size_t ws_size,
                              hipStream_t stream) {
  const int* x      = (const int*)d_in[0];
  const float* emb  = (const float*)d_in[1];
  const float* qrot = (const float*)d_in[2];
  const float* krot = (const float*)d_in[3];
  const float* vrot = (const float*)d_in[4];
  const float* ffr  = (const float*)d_in[5];
  const float* ffi  = (const float*)d_in[6];
  const float* wr   = (const float*)d_in[7];
  const float* br   = (const float*)d_in[8];
  const float* wi   = (const float*)d_in[9];
  const float* bi   = (const float*)d_in[10];
  float* out = (float*)d_out;
  char* ws = (char*)d_ws;

  unsigned short* Wb = (unsigned short*)ws;                 // 32,768,000 B
  float* bias = (float*)(ws + 32768000);                    //    128,000 B
  float* Sb = (float*)(ws + 32896000);
  float* Qb = Sb + (size_t)ROWS * KK;
  float* Kb = Qb + (size_t)ROWS * KK;
  float* Vb = Kb + (size_t)ROWS * KK;
  float* S2 = Vb + (size_t)ROWS * KK;
  unsigned short* Xb = (unsigned short*)(S2 + (size_t)ROWS * KK);
  float* rotcs = S2;   // 6*256 floats scratch; k_embed reads before k_attn writes S2

  k_prep<<<dim3(VOC * 128 / 256), dim3(256), 0, stream>>>(wr, wi, br, bi, qrot, krot, vrot, Wb, bias, rotcs);
  k_embed<<<dim3(ROWS), dim3(256), 0, stream>>>(x, emb, rotcs, Sb, Qb, Kb, Vb);
  k_attn<<<dim3(NB * 8), dim3(512), 0, stream>>>(Qb, Kb, Vb, Sb, S2);
  k_ffnorm<<<dim3(ROWS / 8), dim3(256), 0, stream>>>(S2, ffr, ffi, Xb);
  k_gemm<<<dim3(8000), dim3(256), 0, stream>>>(Xb, Wb, bias, out);
}